// Round 2
// baseline (357.940 us; speedup 1.0000x reference)
//
#include <hip/hip_runtime.h>
#include <math.h>
#include <stdlib.h>

// ---------------- constants ----------------
#define ECOMf 4.59925f
#define M0Bf  2.01026f
#define M0Cf  0.13957061f
#define M0Df  2.00685f

struct cf { float x, y; };
__device__ __forceinline__ cf cmul(cf a, cf b){ return {a.x*b.x - a.y*b.y, a.x*b.y + a.y*b.x}; }
__device__ __forceinline__ cf cmulr(cf a, float s){ return {a.x*s, a.y*s}; }
__device__ __forceinline__ cf cadd(cf a, cf b){ return {a.x+b.x, a.y+b.y}; }
__device__ __forceinline__ cf cconj(cf a){ return {a.x, -a.y}; }

// ---- guaranteed compile-time unroller: every index is a template constant ----
template<int I> struct ic { static constexpr int v = I; };
template<int N, int I=0, typename F>
__device__ __forceinline__ void U(F&& f){
  if constexpr (I < N) { f(ic<I>{}); U<N, I+1>(f); }
}
// e^{-i m phi} power by index im = m+1 (m in {-1,0,1}); e = e^{-i phi}
template<int IM> __device__ __forceinline__ cf phmT(cf e){
  if constexpr (IM == 1) { return cf{1.f, 0.f}; }
  else if constexpr (IM == 2) { return e; }
  else { return cconj(e); }
}

// d^1 matrix entry [R][Cc], R,Cc in 0..2; A2=(1+cb)/2, B2=(1-cb)/2, AB=sqrt(2 A2 B2), CC=A2-B2
template<int R, int Cc>
__device__ __forceinline__ float d1v(float A2, float AB, float B2, float CC){
  if constexpr (R==0){ if constexpr (Cc==0) return A2;  else if constexpr (Cc==1) return AB;  else return B2; }
  else if constexpr (R==1){ if constexpr (Cc==0) return -AB; else if constexpr (Cc==1) return CC;  else return AB; }
  else { if constexpr (Cc==0) return B2;  else if constexpr (Cc==1) return -AB; else return A2; }
}
__device__ __forceinline__ void d1s(float cb, float& A2, float& AB, float& B2, float& CC){
  A2 = fminf(1.f, fmaxf(0.f, 0.5f*(1.f+cb)));
  B2 = fminf(1.f, fmaxf(0.f, 0.5f*(1.f-cb)));
  AB = 1.4142135623730951f * sqrtf(A2*B2);
  CC = A2 - B2;
}
// d^2 scalars
struct D2v { float A4, a3, u6, b3, B4, c1, t6, c2, c0; };
__device__ __forceinline__ D2v d2s(float cb){
  float A2 = fminf(1.f, fmaxf(0.f, 0.5f*(1.f+cb)));
  float B2 = fminf(1.f, fmaxf(0.f, 0.5f*(1.f-cb)));
  float u  = A2*B2;
  float AB = sqrtf(u);
  const float r6 = 2.449489742783178f;
  D2v d;
  d.A4 = A2*A2;  d.B4 = B2*B2;
  d.a3 = 2.f*A2*AB;  d.b3 = 2.f*B2*AB;
  d.t6 = r6*AB*(A2-B2);  d.u6 = r6*u;
  d.c1 = d.A4 - 3.f*u;  d.c2 = 3.f*u - d.B4;  d.c0 = d.A4 - 4.f*u + d.B4;
  return d;
}
// d^2 matrix entry [R][Cc], R in 0..4, Cc in 0..4 (we use 0..3)
template<int R, int Cc>
__device__ __forceinline__ float d2vv(const D2v& d){
  if constexpr (R==0){
    if constexpr (Cc==0) return d.A4; else if constexpr (Cc==1) return d.a3;
    else if constexpr (Cc==2) return d.u6; else if constexpr (Cc==3) return d.b3; else return d.B4;
  } else if constexpr (R==1){
    if constexpr (Cc==0) return -d.a3; else if constexpr (Cc==1) return d.c1;
    else if constexpr (Cc==2) return d.t6; else if constexpr (Cc==3) return d.c2; else return d.b3;
  } else if constexpr (R==2){
    if constexpr (Cc==0) return d.u6; else if constexpr (Cc==1) return -d.t6;
    else if constexpr (Cc==2) return d.c0; else if constexpr (Cc==3) return d.t6; else return d.u6;
  } else if constexpr (R==3){
    if constexpr (Cc==0) return -d.b3; else if constexpr (Cc==1) return d.c2;
    else if constexpr (Cc==2) return -d.t6; else if constexpr (Cc==3) return d.c1; else return d.a3;
  } else {
    if constexpr (Cc==0) return d.B4; else if constexpr (Cc==1) return -d.b3;
    else if constexpr (Cc==2) return d.u6; else if constexpr (Cc==3) return -d.a3; else return d.A4;
  }
}

struct Consts {
  float zcF1[3][2];
  float zcF2[3][3][3];
  float zc_q0rt, zc_q0nd, zc_q0bw;
  float d2F1[5][3][5];
  float d2F2[3];
  float d2_q0rt, d2_q0nd;
  float d1F1[3][3][3];
  float d1F2[3][2];
  float d1_q0rt, d1_q0nd;
};
struct Ptrs { const float* p[28]; };

__device__ __forceinline__ float getqf(float m, float m1, float m2){
  float ms = m1+m2, md = m1-m2;
  return sqrtf((m+ms)*(m-ms)*(m+md)*(m-md))/(2.f*m);
}
__device__ __forceinline__ float barrier2f(float z){ return 9.f + (3.f+z)*z; }
__device__ __forceinline__ float barrier4f(float z){ return z*(z*(z*(z+10.f)+135.f)+1575.f)+11025.f; }
__device__ __forceinline__ float rad2f(float q, float q0){
  float z = 9.f*q*q, z0 = 9.f*q0*q0;
  return q*q*sqrtf(barrier2f(z0)/barrier2f(z));
}
__device__ __forceinline__ float rad4f(float q, float q0){
  float z = 9.f*q*q, z0 = 9.f*q0*q0;
  float q2 = q*q;
  return q2*q2*sqrtf(barrier4f(z0)/barrier4f(z));
}
__device__ __forceinline__ cf epha(float a){  // exp(-i a)
  float s, c;
  __sincosf(a, &s, &c);
  return {c, -s};
}
__device__ __forceinline__ cf ldg(const float* __restrict__ gls, int i){
  return cf{ gls[2*i], gls[2*i+1] };
}

// ---------------- kernel ----------------
__launch_bounds__(256, 2)
__global__ void amp_kernel(Ptrs P, Consts C, float* __restrict__ out, int N){
  int n = blockIdx.x * blockDim.x + threadIdx.x;
  float psum = 0.f;
  if (n < N) {
    const float* __restrict__ gls = P.p[27];

    cf amp[2][3][3];
    U<2>([&](auto A_){ U<3>([&](auto E_){ U<3>([&](auto F_){
      amp[A_.v][E_.v][F_.v] = cf{0.f, 0.f}; }); }); });

    //=========== Zc_4025 (BD chain, Jr=1) ===========
    {
      const float m    = P.p[8][n];
      const float phiA = P.p[9][n];
      const float cosA = P.p[10][n];
      const float phiR = P.p[11][n];
      const float cosR = P.p[12][n];
      const float aB   = P.p[13][n];
      const float cbB  = P.p[14][n];
      const float gB   = P.p[15][n];
      const float aD   = P.p[16][n];
      const float cbD  = P.p[17][n];
      const float gD   = P.p[18][n];

      cf g0 = ldg(gls,0), g1 = ldg(gls,1), g2 = ldg(gls,2), g3 = ldg(gls,3), g4 = ldg(gls,4);

      float q_rt = getqf(ECOMf, M0Cf, m);
      float q_nd = getqf(m, M0Bf, M0Df);
      float r2rt = rad2f(q_rt, C.zc_q0rt);
      float r2nd = rad2f(q_nd, C.zc_q0nd);

      // Breit-Wigner (L=0)
      float width = 0.025f * (q_nd / C.zc_q0bw) * (4.026f / m);
      float dre = m*m - 4.026f*4.026f, dim_ = 4.026f*width;
      float inv = 1.f/(dre*dre + dim_*dim_);
      cf bw = { dre*inv, -dim_*inv };

      cf eA = epha(phiA), eR = epha(phiR), eBa = epha(aB), eBg = epha(gB), eDa = epha(aD), eDg = epha(gD);
      cf U0 = cmul(bw, cconj(eA));   // a = -1
      cf U1 = cmul(bw, eA);          // a = +1

      float aA2,aAB,aB2,aCC; d1s(cosA, aA2,aAB,aB2,aCC);
      float rA2,rAB,rB2,rCC; d1s(cosR, rA2,rAB,rB2,rCC);
      float bA2,bAB,bB2,bCC; d1s(cbB,  bA2,bAB,bB2,bCC);
      float vA2,vAB,vB2,vCC; d1s(cbD,  vA2,vAB,vB2,vCC);

      // F2[p][w] (no phases)
      cf F2[3][3];
      U<3>([&](auto P_){ constexpr int ip = P_.v; U<3>([&](auto W_){ constexpr int iw = W_.v;
        cf t = cmulr(g2, C.zcF2[ip][iw][0]);
        t = cadd(t, cmulr(g3, C.zcF2[ip][iw][1]*r2nd));
        t = cadd(t, cmulr(g4, C.zcF2[ip][iw][2]*r2nd));
        F2[ip][iw] = t; }); });

      // DBf[p][e] = dB[p][e] * e^{-i p aB} * e^{-i e gB}
      cf DBf[3][3];
      U<3>([&](auto P_){ constexpr int ip = P_.v; cf pp = phmT<ip>(eBa);
        U<3>([&](auto E_){ constexpr int ie = E_.v;
          DBf[ip][ie] = cmulr(cmul(pp, phmT<ie>(eBg)), d1v<ip,ie>(bA2,bAB,bB2,bCC)); }); });

      // DDf[w][f] = dD[w][f] * e^{-i w aD} * e^{-i f gD}
      cf DDf[3][3];
      U<3>([&](auto W_){ constexpr int iw = W_.v; cf pw = phmT<iw>(eDa);
        U<3>([&](auto F_){ constexpr int jf = F_.v;
          DDf[iw][jf] = cmulr(cmul(pw, phmT<jf>(eDg)), d1v<iw,jf>(vA2,vAB,vB2,vCC)); }); });

      U<3>([&](auto R_){ constexpr int ir = R_.v;
        cf F1 = cadd(cmulr(g0, C.zcF1[ir][0]), cmulr(g1, C.zcF1[ir][1]*r2rt));
        cf Zr = cmul(F1, phmT<ir>(eR));
        cf za0 = cmulr(cmul(Zr, U0), d1v<0,ir>(aA2,aAB,aB2,aCC));
        cf za1 = cmulr(cmul(Zr, U1), d1v<2,ir>(aA2,aAB,aB2,aCC));
        U<3>([&](auto P_){ constexpr int ip = P_.v;
          cf G[3] = { {0.f,0.f}, {0.f,0.f}, {0.f,0.f} };
          U<3>([&](auto W_){ constexpr int iw = W_.v;
            if constexpr (ip-iw >= -1 && ip-iw <= 1){
              cf t = cmulr(F2[ip][iw], d1v<ir, ip-iw+1>(rA2,rAB,rB2,rCC));
              U<3>([&](auto F_){ constexpr int jf = F_.v;
                G[jf] = cadd(G[jf], cmul(t, DDf[iw][jf])); });
            } });
          U<3>([&](auto E_){ constexpr int ie = E_.v;
            cf c0 = cmul(za0, DBf[ip][ie]);
            cf c1 = cmul(za1, DBf[ip][ie]);
            U<3>([&](auto F_){ constexpr int jf = F_.v;
              amp[0][ie][jf] = cadd(amp[0][ie][jf], cmul(c0, G[jf]));
              amp[1][ie][jf] = cadd(amp[1][ie][jf], cmul(c1, G[jf])); }); });
        });
      });
    }

    //=========== D2_2460 (BC chain, Jr=2) ===========
    {
      const float m    = P.p[0][n];
      const float phiA = P.p[1][n];
      const float cosA = P.p[2][n];
      const float phiR = P.p[3][n];
      const float cosR = P.p[4][n];
      const float aB   = P.p[5][n];
      const float cbB  = P.p[6][n];
      const float gB   = P.p[7][n];

      cf g5 = ldg(gls,5), g6 = ldg(gls,6), g7 = ldg(gls,7), g8 = ldg(gls,8), g9 = ldg(gls,9), g10 = ldg(gls,10);

      float q_rt = getqf(ECOMf, M0Df, m);
      float q_nd = getqf(m, M0Bf, M0Cf);
      float r2rt = rad2f(q_rt, C.d2_q0rt);
      float r4rt = rad4f(q_rt, C.d2_q0rt);
      float r2nd = rad2f(q_nd, C.d2_q0nd);

      // Breit-Wigner (L=2)
      float q0 = C.d2_q0nd;
      float z = 9.f*q_nd*q_nd, z0 = 9.f*q0*q0;
      float bpr2 = barrier2f(z0)/barrier2f(z);
      float qr = q_nd/q0;
      float width = 0.0475f * qr*qr*qr*qr*qr * (2.4607f/m) * bpr2;
      float dre = m*m - 2.4607f*2.4607f, dim_ = 2.4607f*width;
      float inv = 1.f/(dre*dre + dim_*dim_);
      cf bw = { dre*inv, -dim_*inv };

      cf eA = epha(phiA), eR = epha(phiR), eBa = epha(aB), eBg = epha(gB);
      cf eR2 = cmul(eR, eR);

      float aA2,aAB,aB2,aCC; d1s(cosA, aA2,aAB,aB2,aCC);
      float bA2,bAB,bB2,bCC; d1s(cbB,  bA2,bAB,bB2,bCC);
      D2v dR2 = d2s(cosR);

      cf F2ph[3];
      U<3>([&](auto P_){ constexpr int ip = P_.v;
        F2ph[ip] = cmul(cmulr(g10, C.d2F2[ip]*r2nd), phmT<ip>(eBa)); });

      // dBg[p][e] = dB[p][e] * e^{-i e gB}
      cf dBg[3][3];
      U<3>([&](auto P_){ constexpr int ip = P_.v;
        U<3>([&](auto E_){ constexpr int ie = E_.v;
          dBg[ip][ie] = cmulr(phmT<ie>(eBg), d1v<ip,ie>(bA2,bAB,bB2,bCC)); }); });

      U<5>([&](auto R_){ constexpr int ir = R_.v;
        cf pr;
        if constexpr (ir==0) pr = cconj(eR2);
        else if constexpr (ir==1) pr = cconj(eR);
        else if constexpr (ir==2) pr = cf{1.f,0.f};
        else if constexpr (ir==3) pr = eR;
        else pr = eR2;
        cf zb  = cmul(bw, pr);
        cf Zb0 = cmul(zb, cconj(eA));
        cf Zb1 = cmul(zb, eA);

        cf Wr[3] = { {0.f,0.f}, {0.f,0.f}, {0.f,0.f} };
        U<3>([&](auto P_){ constexpr int ip = P_.v;
          cf t = cmulr(F2ph[ip], d2vv<ir, ip+1>(dR2));
          U<3>([&](auto E_){ constexpr int ie = E_.v;
            Wr[ie] = cadd(Wr[ie], cmul(t, dBg[ip][ie])); }); });

        U<3>([&](auto F_){ constexpr int jf = F_.v;
          constexpr int k = (ir-2) - (jf-1);
          if constexpr (k >= -1 && k <= 1){
            cf zf = cmulr(g5, C.d2F1[ir][jf][0]);
            zf = cadd(zf, cmulr(g6, C.d2F1[ir][jf][1]*r2rt));
            zf = cadd(zf, cmulr(g7, C.d2F1[ir][jf][2]*r2rt));
            zf = cadd(zf, cmulr(g8, C.d2F1[ir][jf][3]*r2rt));
            zf = cadd(zf, cmulr(g9, C.d2F1[ir][jf][4]*r4rt));
            cf z0 = cmulr(cmul(zf, Zb0), d1v<0,k+1>(aA2,aAB,aB2,aCC));
            cf z1 = cmulr(cmul(zf, Zb1), d1v<2,k+1>(aA2,aAB,aB2,aCC));
            U<3>([&](auto E_){ constexpr int ie = E_.v;
              amp[0][ie][jf] = cadd(amp[0][ie][jf], cmul(z0, Wr[ie]));
              amp[1][ie][jf] = cadd(amp[1][ie][jf], cmul(z1, Wr[ie])); });
          } });
      });
    }

    //=========== D1_2430 (CD chain, Jr=1) ===========
    {
      const float m    = P.p[19][n];
      const float phiA = P.p[20][n];
      const float cosA = P.p[21][n];
      const float phiR = P.p[22][n];
      const float cosR = P.p[23][n];
      const float aD   = P.p[24][n];
      const float cbD  = P.p[25][n];
      const float gD   = P.p[26][n];

      cf g11 = ldg(gls,11), g12 = ldg(gls,12), g13 = ldg(gls,13), g14 = ldg(gls,14), g15 = ldg(gls,15);

      float q_rt = getqf(ECOMf, M0Bf, m);
      float q_nd = getqf(m, M0Cf, M0Df);
      float r2rt = rad2f(q_rt, C.d1_q0rt);
      float r2nd = rad2f(q_nd, C.d1_q0nd);

      // Breit-Wigner (L=0)
      float width = 0.384f * (q_nd / C.d1_q0nd) * (2.427f/m);
      float dre = m*m - 2.427f*2.427f, dim_ = 2.427f*width;
      float inv = 1.f/(dre*dre + dim_*dim_);
      cf bw = { dre*inv, -dim_*inv };

      cf eA = epha(phiA), eR = epha(phiR), eDa = epha(aD), eDg = epha(gD);

      float aA2,aAB,aB2,aCC; d1s(cosA, aA2,aAB,aB2,aCC);
      float rA2,rAB,rB2,rCC; d1s(cosR, rA2,rAB,rB2,rCC);
      float vA2,vAB,vB2,vCC; d1s(cbD,  vA2,vAB,vB2,vCC);

      cf F2ph[3];
      U<3>([&](auto W_){ constexpr int iw = W_.v;
        cf t = cadd(cmulr(g14, C.d1F2[iw][0]), cmulr(g15, C.d1F2[iw][1]*r2nd));
        F2ph[iw] = cmul(t, phmT<iw>(eDa)); });

      // dDg[w][f] = dD[w][f] * e^{-i f gD}
      cf dDg[3][3];
      U<3>([&](auto W_){ constexpr int iw = W_.v;
        U<3>([&](auto F_){ constexpr int jf = F_.v;
          dDg[iw][jf] = cmulr(phmT<jf>(eDg), d1v<iw,jf>(vA2,vAB,vB2,vCC)); }); });

      U<3>([&](auto R_){ constexpr int ir = R_.v;
        cf zb  = cmul(bw, phmT<ir>(eR));
        cf Zb0 = cmul(zb, cconj(eA));
        cf Zb1 = cmul(zb, eA);

        cf Gr[3] = { {0.f,0.f}, {0.f,0.f}, {0.f,0.f} };
        U<3>([&](auto W_){ constexpr int iw = W_.v;
          cf t = cmulr(F2ph[iw], d1v<ir,iw>(rA2,rAB,rB2,rCC));
          U<3>([&](auto F_){ constexpr int jf = F_.v;
            Gr[jf] = cadd(Gr[jf], cmul(t, dDg[iw][jf])); }); });

        U<3>([&](auto E_){ constexpr int ie = E_.v;
          constexpr int k = ir - ie;
          if constexpr (k >= -1 && k <= 1){
            cf ze = cmulr(g11, C.d1F1[ir][ie][0]);
            ze = cadd(ze, cmulr(g12, C.d1F1[ir][ie][1]*r2rt));
            ze = cadd(ze, cmulr(g13, C.d1F1[ir][ie][2]*r2rt));
            cf z0 = cmulr(cmul(ze, Zb0), d1v<0,k+1>(aA2,aAB,aB2,aCC));
            cf z1 = cmulr(cmul(ze, Zb1), d1v<2,k+1>(aA2,aAB,aB2,aCC));
            U<3>([&](auto F_){ constexpr int jf = F_.v;
              amp[0][ie][jf] = cadd(amp[0][ie][jf], cmul(z0, Gr[jf]));
              amp[1][ie][jf] = cadd(amp[1][ie][jf], cmul(z1, Gr[jf])); });
          } });
      });
    }

    U<2>([&](auto A_){ U<3>([&](auto E_){ U<3>([&](auto F_){
      cf a = amp[A_.v][E_.v][F_.v];
      psum += a.x*a.x + a.y*a.y; }); }); });
  }

  // wave + block reduction, one atomic per block
  #pragma unroll
  for (int off=32; off>0; off>>=1) psum += __shfl_down(psum, off, 64);
  __shared__ float red[4];
  int lane = threadIdx.x & 63, wid = threadIdx.x >> 6;
  if (lane == 0) red[wid] = psum;
  __syncthreads();
  if (threadIdx.x == 0) atomicAdd(out, red[0]+red[1]+red[2]+red[3]);
}

// ---------------- host-side constant generation ----------------
static double factd(int n){ double r=1.0; for (int i=2;i<=n;++i) r*=i; return r; }

static double cgc(int j1,int j2,int m1,int m2,int j,int m){
  if (m1+m2 != m || j < abs(j1-j2) || j > j1+j2) return 0.0;
  if (abs(m1)>j1 || abs(m2)>j2 || abs(m)>j) return 0.0;
  double pref = sqrt((2.0*j+1.0)*factd(j+j1-j2)*factd(j-j1+j2)*factd(j1+j2-j)/factd(j1+j2+j+1));
  pref *= sqrt(factd(j+m)*factd(j-m)*factd(j1-m1)*factd(j1+m1)*factd(j2-m2)*factd(j2+m2));
  double tot = 0.0;
  for (int k=0; k<=j1+j2-j; ++k){
    int d0=k, d1=j1+j2-j-k, d2=j1-m1-k, d3=j2+m2-k, d4=j-j2+m1+k, d5=j-j1-m2+k;
    if (d0<0||d1<0||d2<0||d3<0||d4<0||d5<0) continue;
    double p = factd(d0)*factd(d1)*factd(d2)*factd(d3)*factd(d4)*factd(d5);
    tot += ((k&1)? -1.0 : 1.0)/p;
  }
  return pref*tot;
}

static double getq_h(double m, double m1, double m2){
  double ms=m1+m2, md=m1-m2;
  return sqrt((m+ms)*(m-ms)*(m+md)*(m-md))/(2.0*m);
}

static void fill_consts(Consts& C){
  const double EC=4.59925, MB=2.01026, MC=0.13957061, MD=2.00685;
  {
    const int ls0[2][2] = {{0,1},{2,1}};
    for (int ir=0; ir<3; ++ir){
      int r = ir-1;
      for (int i=0;i<2;++i){
        int l=ls0[i][0], s=ls0[i][1];
        C.zcF1[ir][i] = (float)( sqrt((2.0*l+1.0)/3.0)*cgc(1,0,r,0,s,r)*cgc(l,s,0,r,1,r) );
      }
    }
    const int ls1[3][2] = {{0,1},{2,1},{2,2}};
    for (int ip=0; ip<3; ++ip) for (int iw=0; iw<3; ++iw){
      int p=ip-1, w=iw-1;
      for (int i=0;i<3;++i){
        int l=ls1[i][0], s=ls1[i][1];
        C.zcF2[ip][iw][i] = (float)( sqrt((2.0*l+1.0)/3.0)*cgc(1,1,p,-w,s,p-w)*cgc(l,s,0,p-w,1,p-w) );
      }
    }
    C.zc_q0rt = (float)getq_h(EC, MC, 4.026);
    C.zc_q0nd = (float)getq_h(4.026, MB, MC);
    C.zc_q0bw = (float)getq_h(4.026, MB, MD);
  }
  {
    const int ls0[5][2] = {{0,1},{2,1},{2,2},{2,3},{4,3}};
    for (int ir=0; ir<5; ++ir) for (int jf=0; jf<3; ++jf){
      int r=ir-2, f3=jf-1;
      for (int i=0;i<5;++i){
        int l=ls0[i][0], s=ls0[i][1];
        C.d2F1[ir][jf][i] = (float)( sqrt((2.0*l+1.0)/3.0)*cgc(2,1,r,-f3,s,r-f3)*cgc(l,s,0,r-f3,1,r-f3) );
      }
    }
    for (int ip=0; ip<3; ++ip){
      int p=ip-1;
      C.d2F2[ip] = (float)( cgc(1,0,p,0,1,p)*cgc(2,1,0,p,2,p) );
    }
    C.d2_q0rt = (float)getq_h(EC, MD, 2.4607);
    C.d2_q0nd = (float)getq_h(2.4607, MB, MC);
  }
  {
    const int ls0[3][2] = {{0,1},{2,1},{2,2}};
    for (int ir=0; ir<3; ++ir) for (int ie=0; ie<3; ++ie){
      int r=ir-1, e=ie-1;
      for (int i=0;i<3;++i){
        int l=ls0[i][0], s=ls0[i][1];
        C.d1F1[ir][ie][i] = (float)( sqrt((2.0*l+1.0)/3.0)*cgc(1,1,r,-e,s,r-e)*cgc(l,s,0,r-e,1,r-e) );
      }
    }
    const int ls1[2][2] = {{0,1},{2,1}};
    for (int iw=0; iw<3; ++iw){
      int w=iw-1;
      for (int i=0;i<2;++i){
        int l=ls1[i][0], s=ls1[i][1];
        C.d1F2[iw][i] = (float)( sqrt((2.0*l+1.0)/3.0)*cgc(0,1,w,0,s,w)*cgc(l,s,0,w,1,w) );
      }
    }
    C.d1_q0rt = (float)getq_h(EC, MB, 2.427);
    C.d1_q0nd = (float)getq_h(2.427, MC, MD);
  }
}

// ---------------- launch ----------------
extern "C" void kernel_launch(void* const* d_in, const int* in_sizes, int n_in,
                              void* d_out, int out_size, void* d_ws, size_t ws_size,
                              hipStream_t stream){
  (void)n_in; (void)d_ws; (void)ws_size;
  Ptrs P;
  for (int i=0; i<28; ++i) P.p[i] = (const float*)d_in[i];
  Consts C;
  fill_consts(C);
  int N = in_sizes[0];
  hipMemsetAsync(d_out, 0, (size_t)out_size * sizeof(float), stream);
  int grid = (N + 255) / 256;
  amp_kernel<<<grid, 256, 0, stream>>>(P, C, (float*)d_out, N);
}